// Round 1
// baseline (5717.322 us; speedup 1.0000x reference)
//
#include <hip/hip_runtime.h>
#include <hip/hip_bf16.h>

// Problem constants (from reference)
#define Bq 256
#define Iq 64
#define Tq 16
#define Vq 4096
#define Eq 256
#define Hq 256
#define Gq 1024   // 4*H

__device__ __forceinline__ float sigf(float x) {
    return __builtin_amdgcn_rcpf(1.f + __expf(-x));
}
__device__ __forceinline__ float tanh_fast(float x) {
    float e = __expf(2.f * x);
    return 1.f - 2.f * __builtin_amdgcn_rcpf(e + 1.f);
}

// ---------------------------------------------------------------------------
// K0: transpose weights into [k][g] layout for coalesced inner-loop reads.
// WihT_tok[256][1024], WhhT_tok[256][1024], WT_ins[512][1024] = {WihT; WhhT}.
__global__ void k_transpose(const float* __restrict__ Wih_tok,
                            const float* __restrict__ Whh_tok,
                            const float* __restrict__ Wih_ins,
                            const float* __restrict__ Whh_ins,
                            float* __restrict__ WihT_tok,
                            float* __restrict__ WhhT_tok,
                            float* __restrict__ WT_ins) {
    int g = blockIdx.x;   // 0..1023
    int k = threadIdx.x;  // 0..255
    WihT_tok[k * Gq + g]      = Wih_tok[g * Hq + k];
    WhhT_tok[k * Gq + g]      = Whh_tok[g * Hq + k];
    WT_ins[k * Gq + g]        = Wih_ins[g * Hq + k];
    WT_ins[(k + Hq) * Gq + g] = Whh_ins[g * Hq + k];
}

// ---------------------------------------------------------------------------
// K1: Epre[v][g] = dot(emb[v,:], Wih_tok[g,:]) + b_tok[g]   (V x 4H)
// 512 blocks x 256 thr, 8 vocab rows per block.
__global__ __launch_bounds__(256) void k_epre(const float* __restrict__ emb,
                                              const float* __restrict__ WihT,
                                              const float* __restrict__ b_tok,
                                              float* __restrict__ Epre) {
    __shared__ __align__(16) float es[8][Eq];
    int tid = threadIdx.x;
    int v0 = blockIdx.x * 8;
    #pragma unroll
    for (int r = 0; r < 8; ++r) es[r][tid] = emb[(v0 + r) * Eq + tid];
    __syncthreads();
    float a0[8] = {}, a1[8] = {}, a2[8] = {}, a3[8] = {};
    const float* wp = WihT + tid;
    #pragma unroll 4
    for (int k = 0; k < Eq; ++k) {
        float w0 = wp[0], w1 = wp[256], w2 = wp[512], w3 = wp[768];
        wp += Gq;
        #pragma unroll
        for (int r = 0; r < 8; ++r) {
            float e = es[r][k];
            a0[r] += w0 * e; a1[r] += w1 * e; a2[r] += w2 * e; a3[r] += w3 * e;
        }
    }
    float b0 = b_tok[tid], b1 = b_tok[tid + 256], b2 = b_tok[tid + 512], b3 = b_tok[tid + 768];
    #pragma unroll
    for (int r = 0; r < 8; ++r) {
        float* op = Epre + (size_t)(v0 + r) * Gq;
        op[tid]       = a0[r] + b0;
        op[tid + 256] = a1[r] + b1;
        op[tid + 512] = a2[r] + b2;
        op[tid + 768] = a3[r] + b3;
    }
}

// ---------------------------------------------------------------------------
// K2: token-level LSTM. 16384 independent sequences, 16 steps.
// 1024 blocks x 256 thr, 16 seqs/block. Thread tid owns hidden unit j=tid for
// all 16 seqs: computes the 4 gates (rows j, 256+j, 512+j, 768+j) and the
// elementwise update locally (c in registers). h lives in LDS [unit][seq]
// (pad 20 -> 16B-aligned rows, float4 broadcast reads in the k-loop).
#define SPB 16
#define HPAD 20
__global__ __launch_bounds__(256) void k_token_lstm(
        const int* __restrict__ tokens,     // [16384][16]
        const int* __restrict__ tok_len,    // [16384]
        const float* __restrict__ Epre,     // [V][1024]
        const float* __restrict__ WhhT,     // [256][1024]
        float* __restrict__ instr_repr) {   // [16384][256]
    __shared__ __align__(16) float hs[Hq][HPAD];
    __shared__ int toks[SPB][Tq];
    __shared__ int lens[SPB];
    int tid = threadIdx.x;
    int s0 = blockIdx.x * SPB;

    #pragma unroll
    for (int s = 0; s < SPB; ++s) hs[tid][s] = 0.f;
    {
        int s = tid >> 4, t = tid & 15;  // 256 threads cover 16x16 token grid
        toks[s][t] = tokens[(s0 + s) * Tq + t];
        if (tid < SPB) lens[tid] = tok_len[s0 + tid];
    }
    float c[SPB];
    #pragma unroll
    for (int s = 0; s < SPB; ++s) c[s] = 0.f;
    __syncthreads();

    for (int t = 0; t < Tq; ++t) {
        float ai[SPB] = {}, af[SPB] = {}, ag[SPB] = {}, ao[SPB] = {};
        const float* wp = WhhT + tid;
        #pragma unroll 2
        for (int k = 0; k < Hq; ++k) {
            float w0 = wp[0], w1 = wp[256], w2 = wp[512], w3 = wp[768];
            wp += Gq;
            const float4* hp = (const float4*)(&hs[k][0]);
            float4 h0 = hp[0], h1 = hp[1], h2 = hp[2], h3 = hp[3];
            float hv[16] = {h0.x, h0.y, h0.z, h0.w, h1.x, h1.y, h1.z, h1.w,
                            h2.x, h2.y, h2.z, h2.w, h3.x, h3.y, h3.z, h3.w};
            #pragma unroll
            for (int s = 0; s < SPB; ++s) {
                ai[s] += w0 * hv[s];
                af[s] += w1 * hv[s];
                ag[s] += w2 * hv[s];
                ao[s] += w3 * hv[s];
            }
        }
        __syncthreads();  // all lanes done reading hs
        #pragma unroll
        for (int s = 0; s < SPB; ++s) {
            if (t < lens[s]) {   // wave-uniform branch
                int tok = toks[s][t];
                const float* ep = Epre + (size_t)tok * Gq + tid;
                float gi = ai[s] + ep[0];
                float gf = af[s] + ep[256];
                float gg = ag[s] + ep[512];
                float go = ao[s] + ep[768];
                float cn = sigf(gf) * c[s] + sigf(gi) * tanh_fast(gg);
                c[s] = cn;
                hs[tid][s] = sigf(go) * tanh_fast(cn);
            }
        }
        __syncthreads();  // hs updated for next step
    }
    #pragma unroll
    for (int s = 0; s < SPB; ++s) {
        instr_repr[(size_t)(s0 + s) * Hq + tid] = hs[tid][s];
    }
}

// ---------------------------------------------------------------------------
// K3: instruction-level LSTM + final linear. B=256 seqs, 64 steps.
// 64 blocks x 1024 thr, 4 seqs/block (recurrence fully block-local).
// Thread (s = tid>>8, j = tid&255) owns unit j of seq s. K=512 fused (x;h).
__global__ __launch_bounds__(1024) void k_instr_lstm(
        const float* __restrict__ instr_repr,  // [256][64][256]
        const int* __restrict__ instr_cnt,     // [256]
        const float* __restrict__ WT,          // [512][1024]
        const float* __restrict__ b_ins,       // [1024]
        const float* __restrict__ linW,        // [256]
        const float* __restrict__ linb,        // [1]
        float* __restrict__ out) {             // [256]
    __shared__ float hs[4][Hq];
    __shared__ float xs[4][Hq];
    __shared__ float red[16];
    int tid = threadIdx.x;
    int s = tid >> 8;
    int j = tid & 255;
    int b = blockIdx.x * 4 + s;
    int len = instr_cnt[b];
    hs[s][j] = 0.f;
    float c = 0.f;
    float bi = b_ins[j], bff = b_ins[j + 256], bg = b_ins[j + 512], bo = b_ins[j + 768];
    __syncthreads();

    for (int i = 0; i < Iq; ++i) {
        xs[s][j] = instr_repr[((size_t)b * Iq + i) * Hq + j];
        __syncthreads();
        float a0 = 0.f, a1 = 0.f, a2 = 0.f, a3 = 0.f;
        const float* wp = WT + j;
        #pragma unroll 8
        for (int k = 0; k < Hq; ++k) {
            float w0 = wp[0], w1 = wp[256], w2 = wp[512], w3 = wp[768];
            wp += Gq;
            float xv = xs[s][k];
            a0 += w0 * xv; a1 += w1 * xv; a2 += w2 * xv; a3 += w3 * xv;
        }
        #pragma unroll 8
        for (int k = 0; k < Hq; ++k) {
            float w0 = wp[0], w1 = wp[256], w2 = wp[512], w3 = wp[768];
            wp += Gq;
            float hv = hs[s][k];
            a0 += w0 * hv; a1 += w1 * hv; a2 += w2 * hv; a3 += w3 * hv;
        }
        __syncthreads();  // done reading hs/xs
        if (i < len) {    // wave-uniform
            float cn = sigf(a1 + bff) * c + sigf(a0 + bi) * tanh_fast(a2 + bg);
            c = cn;
            hs[s][j] = sigf(a3 + bo) * tanh_fast(cn);
        }
        __syncthreads();
    }

    // out[b] = dot(linW, h[b]) + linb
    float p = linW[j] * hs[s][j];
    #pragma unroll
    for (int off = 32; off > 0; off >>= 1) p += __shfl_down(p, off);
    int wid = tid >> 6;  // 16 waves
    if ((tid & 63) == 0) red[wid] = p;
    __syncthreads();
    if (tid < 4) {
        float v = red[tid * 4] + red[tid * 4 + 1] + red[tid * 4 + 2] + red[tid * 4 + 3] + linb[0];
        out[blockIdx.x * 4 + tid] = v;
    }
}

// ---------------------------------------------------------------------------
extern "C" void kernel_launch(void* const* d_in, const int* in_sizes, int n_in,
                              void* d_out, int out_size, void* d_ws, size_t ws_size,
                              hipStream_t stream) {
    const int*   tokens  = (const int*)d_in[0];
    const int*   icnt    = (const int*)d_in[1];
    const int*   tcnt    = (const int*)d_in[2];
    const float* emb     = (const float*)d_in[3];
    const float* Wih_tok = (const float*)d_in[4];
    const float* Whh_tok = (const float*)d_in[5];
    const float* b_tok   = (const float*)d_in[6];
    const float* Wih_ins = (const float*)d_in[7];
    const float* Whh_ins = (const float*)d_in[8];
    const float* b_ins   = (const float*)d_in[9];
    const float* linW    = (const float*)d_in[10];
    const float* linb    = (const float*)d_in[11];
    float* out = (float*)d_out;

    float* ws = (float*)d_ws;
    float* WihT_tok   = ws;                       // 256*1024
    float* WhhT_tok   = WihT_tok + 256 * 1024;    // 256*1024
    float* WT_ins     = WhhT_tok + 256 * 1024;    // 512*1024
    float* Epre       = WT_ins + 512 * 1024;      // 4096*1024
    float* instr_repr = Epre + 4096 * 1024;       // 16384*256
    size_t need = (size_t)(256 * 1024 * 2 + 512 * 1024 + 4096 * 1024 + 16384 * 256) * 4;
    if (ws_size < need) return;  // workspace too small; fail loudly via absmax

    hipLaunchKernelGGL(k_transpose, dim3(1024), dim3(256), 0, stream,
                       Wih_tok, Whh_tok, Wih_ins, Whh_ins, WihT_tok, WhhT_tok, WT_ins);
    hipLaunchKernelGGL(k_epre, dim3(512), dim3(256), 0, stream,
                       emb, WihT_tok, b_tok, Epre);
    hipLaunchKernelGGL(k_token_lstm, dim3(1024), dim3(256), 0, stream,
                       tokens, tcnt, Epre, WhhT_tok, instr_repr);
    hipLaunchKernelGGL(k_instr_lstm, dim3(64), dim3(1024), 0, stream,
                       instr_repr, icnt, WT_ins, b_ins, linW, linb, out);
}

// Round 3
// 2665.984 us; speedup vs baseline: 2.1445x; 2.1445x over previous
//
#include <hip/hip_runtime.h>
#include <hip/hip_bf16.h>

// Problem constants (from reference)
#define Bq 256
#define Iq 64
#define Tq 16
#define Vq 4096
#define Eq 256
#define Hq 256
#define Gq 1024   // 4*H
#define HPAD 20   // hs row pad (80B, 16B-aligned)

__device__ __forceinline__ float sigf(float x) {
    return __builtin_amdgcn_rcpf(1.f + __expf(-x));
}
__device__ __forceinline__ float tanh_fast(float x) {
    float e = __expf(2.f * x);
    return 1.f - 2.f * __builtin_amdgcn_rcpf(e + 1.f);
}

// ---------------------------------------------------------------------------
// K0: gate-pack weights. W4[k][j] = float4(Wi[j,k], Wf[j,k], Wg[j,k], Wo[j,k])
// where original W is [1024][K] row-major with rows gate*256+j.
// Also packs biases: b4[j] = (b[j], b[j+256], b[j+512], b[j+768]).
__global__ void k_pack(const float* __restrict__ Wih_tok,
                       const float* __restrict__ Whh_tok,
                       const float* __restrict__ Wih_ins,
                       const float* __restrict__ Whh_ins,
                       const float* __restrict__ b_tok,
                       const float* __restrict__ b_ins,
                       float* __restrict__ Wih4t, float* __restrict__ Whh4t,
                       float* __restrict__ Wih4i, float* __restrict__ Whh4i,
                       float* __restrict__ b4t, float* __restrict__ b4i) {
    int g = blockIdx.x;          // 0..1023 original row
    int q = g >> 8;              // gate 0..3 (i,f,g,o)
    int j = g & 255;             // unit
    int k = threadIdx.x;         // 0..255
    int dst = (k * 256 + j) * 4 + q;
    Wih4t[dst] = Wih_tok[g * Hq + k];
    Whh4t[dst] = Whh_tok[g * Hq + k];
    Wih4i[dst] = Wih_ins[g * Hq + k];
    Whh4i[dst] = Whh_ins[g * Hq + k];
    if (k == 0) {
        b4t[j * 4 + q] = b_tok[g];
        b4i[j * 4 + q] = b_ins[g];
    }
}

// ---------------------------------------------------------------------------
// K1: Epre4[v][j] = float4 of 4 gate pre-activations: emb[v,:]·W + b  (incl bias)
// 512 blocks x 256 thr, 8 vocab rows/block.
__global__ __launch_bounds__(256) void k_epre(const float* __restrict__ emb,
                                              const float4* __restrict__ Wih4t,
                                              const float4* __restrict__ b4t,
                                              float4* __restrict__ Ep4) {
    __shared__ float es[8][Eq];
    int tid = threadIdx.x;
    int v0 = blockIdx.x * 8;
    #pragma unroll
    for (int r = 0; r < 8; ++r) es[r][tid] = emb[(v0 + r) * Eq + tid];
    __syncthreads();
    float4 a[8];
    #pragma unroll
    for (int r = 0; r < 8; ++r) a[r] = make_float4(0.f, 0.f, 0.f, 0.f);
    const float4* Wp = Wih4t + tid;
    #pragma unroll 2
    for (int k = 0; k < Eq; ++k) {
        float4 wv = Wp[k * 256];
        #pragma unroll
        for (int r = 0; r < 8; ++r) {
            float e = es[r][k];
            a[r].x += wv.x * e; a[r].y += wv.y * e;
            a[r].z += wv.z * e; a[r].w += wv.w * e;
        }
    }
    float4 b4 = b4t[tid];
    #pragma unroll
    for (int r = 0; r < 8; ++r) {
        Ep4[(size_t)(v0 + r) * 256 + tid] =
            make_float4(a[r].x + b4.x, a[r].y + b4.y, a[r].z + b4.z, a[r].w + b4.w);
    }
}

// ---------------------------------------------------------------------------
// K2: token-level LSTM, 16 seqs/block, 1024 blocks x 256 thr.
// Thread tid owns hidden unit j=tid for all 16 seqs. Accumulators are 16
// NAMED float4s (4 seq-groups x 4 gates) so the compiler cannot reroll.
// Fused tail: Xp[seq] = Wih_ins·h_final + b_ins (x-projection for instr LSTM).
// NOTE macro params must NOT be named x/y/z/w (float4 member capture!).
#define FMAg(acc, ww, hv) \
    acc.x += (ww) * (hv).x; acc.y += (ww) * (hv).y; \
    acc.z += (ww) * (hv).z; acc.w += (ww) * (hv).w;

#define KSTEP(WPTR, kk) { \
    float4 wv = (WPTR)[(kk) * 256]; \
    const float4* hp = (const float4*)(&hs[kk][0]); \
    float4 h0 = hp[0], h1 = hp[1], h2 = hp[2], h3 = hp[3]; \
    FMAg(aI0, wv.x, h0) FMAg(aI1, wv.x, h1) FMAg(aI2, wv.x, h2) FMAg(aI3, wv.x, h3) \
    FMAg(aF0, wv.y, h0) FMAg(aF1, wv.y, h1) FMAg(aF2, wv.y, h2) FMAg(aF3, wv.y, h3) \
    FMAg(aG0, wv.z, h0) FMAg(aG1, wv.z, h1) FMAg(aG2, wv.z, h2) FMAg(aG3, wv.z, h3) \
    FMAg(aO0, wv.w, h0) FMAg(aO1, wv.w, h1) FMAg(aO2, wv.w, h2) FMAg(aO3, wv.w, h3) }

#define INITS(sg, mm, ss) { \
    float4 e = Ep4[(size_t)toks[ss][t] * 256 + tid]; \
    aI##sg.mm = e.x; aF##sg.mm = e.y; aG##sg.mm = e.z; aO##sg.mm = e.w; }

#define UPDS(sg, mm, ss) if (t < lens[ss]) { \
    float cn = sigf(aF##sg.mm) * c[ss] + sigf(aI##sg.mm) * tanh_fast(aG##sg.mm); \
    c[ss] = cn; \
    hs[tid][ss] = sigf(aO##sg.mm) * tanh_fast(cn); }

#define INITB(sg) { \
    aI##sg = make_float4(eb.x, eb.x, eb.x, eb.x); \
    aF##sg = make_float4(eb.y, eb.y, eb.y, eb.y); \
    aG##sg = make_float4(eb.z, eb.z, eb.z, eb.z); \
    aO##sg = make_float4(eb.w, eb.w, eb.w, eb.w); }

#define STXS(sg, mm, ss) \
    Xp4[(size_t)(s0 + ss) * 256 + tid] = \
        make_float4(aI##sg.mm, aF##sg.mm, aG##sg.mm, aO##sg.mm);

__global__ __launch_bounds__(256, 3) void k_token_lstm(
        const int* __restrict__ tokens,      // [16384][16]
        const int* __restrict__ tok_len,     // [16384]
        const float4* __restrict__ Ep4,      // [V*256] gate-packed (+bias)
        const float4* __restrict__ Whh4t,    // [256*256] gate-packed
        const float4* __restrict__ Wih4i,    // [256*256] gate-packed
        const float4* __restrict__ b4i,      // [256]
        float* __restrict__ instr_repr,      // [16384][256]
        float4* __restrict__ Xp4,            // [16384*256] or unused
        int do_xp) {
    __shared__ __align__(16) float hs[Hq][HPAD];
    __shared__ int toks[16][Tq];
    __shared__ int lens[16];
    int tid = threadIdx.x;
    int s0 = blockIdx.x * 16;

    #pragma unroll
    for (int s = 0; s < 16; ++s) hs[tid][s] = 0.f;
    toks[tid >> 4][tid & 15] = tokens[s0 * Tq + tid];
    if (tid < 16) lens[tid] = tok_len[s0 + tid];
    float c[16];
    #pragma unroll
    for (int s = 0; s < 16; ++s) c[s] = 0.f;
    __syncthreads();

    int tmax = 0;
    #pragma unroll
    for (int s = 0; s < 16; ++s) tmax = max(tmax, lens[s]);

    float4 aI0, aI1, aI2, aI3, aF0, aF1, aF2, aF3;
    float4 aG0, aG1, aG2, aG3, aO0, aO1, aO2, aO3;

    for (int t = 0; t < tmax; ++t) {
        // init accumulators from Epre gather (includes b_tok)
        INITS(0, x, 0)  INITS(0, y, 1)  INITS(0, z, 2)  INITS(0, w, 3)
        INITS(1, x, 4)  INITS(1, y, 5)  INITS(1, z, 6)  INITS(1, w, 7)
        INITS(2, x, 8)  INITS(2, y, 9)  INITS(2, z, 10) INITS(2, w, 11)
        INITS(3, x, 12) INITS(3, y, 13) INITS(3, z, 14) INITS(3, w, 15)
        const float4* Wp = Whh4t + tid;
        #pragma unroll 2
        for (int k = 0; k < Hq; ++k) { KSTEP(Wp, k) }
        __syncthreads();   // all done reading hs
        UPDS(0, x, 0)  UPDS(0, y, 1)  UPDS(0, z, 2)  UPDS(0, w, 3)
        UPDS(1, x, 4)  UPDS(1, y, 5)  UPDS(1, z, 6)  UPDS(1, w, 7)
        UPDS(2, x, 8)  UPDS(2, y, 9)  UPDS(2, z, 10) UPDS(2, w, 11)
        UPDS(3, x, 12) UPDS(3, y, 13) UPDS(3, z, 14) UPDS(3, w, 15)
        __syncthreads();   // hs visible for next step
    }

    #pragma unroll
    for (int s = 0; s < 16; ++s)
        instr_repr[(size_t)(s0 + s) * Hq + tid] = hs[tid][s];

    if (do_xp) {
        // Xp[seq] = Wih_ins · h_final + b_ins  (one extra k-pass)
        float4 eb = b4i[tid];
        INITB(0) INITB(1) INITB(2) INITB(3)
        const float4* Wp2 = Wih4i + tid;
        #pragma unroll 2
        for (int k = 0; k < Hq; ++k) { KSTEP(Wp2, k) }
        STXS(0, x, 0)  STXS(0, y, 1)  STXS(0, z, 2)  STXS(0, w, 3)
        STXS(1, x, 4)  STXS(1, y, 5)  STXS(1, z, 6)  STXS(1, w, 7)
        STXS(2, x, 8)  STXS(2, y, 9)  STXS(2, z, 10) STXS(2, w, 11)
        STXS(3, x, 12) STXS(3, y, 13) STXS(3, z, 14) STXS(3, w, 15)
    }
}

// ---------------------------------------------------------------------------
// K3: instruction-level LSTM + final linear. 256 blocks x 256 thr, 1 seq/block.
// Fast path (fused=1): K=256 recurrence, x comes precomputed from Xp4.
// Fallback (fused=0): K=512, x loaded from instr_repr each step.
__global__ __launch_bounds__(256) void k_instr_lstm(
        const float4* __restrict__ Xp4,        // [16384*256] (fast) or unused
        const float* __restrict__ instr_repr,  // [16384][256] (fallback)
        const int* __restrict__ instr_cnt,     // [256]
        const float4* __restrict__ Wih4i,      // [256*256]
        const float4* __restrict__ Whh4i,      // [256*256]
        const float4* __restrict__ b4i,        // [256]
        const float* __restrict__ linW,        // [256]
        const float* __restrict__ linb,        // [1]
        float* __restrict__ out,               // [256]
        int fused) {
    __shared__ float hs[Hq];
    __shared__ float xs[Hq];
    __shared__ float red[4];
    int tid = threadIdx.x;
    int b = blockIdx.x;
    int len = instr_cnt[b];
    hs[tid] = 0.f;
    float cc = 0.f;
    float4 bb = b4i[tid];
    float4 xcur = make_float4(0.f, 0.f, 0.f, 0.f);
    if (fused) xcur = Xp4[(size_t)b * Iq * 256 + tid];
    __syncthreads();

    for (int i = 0; i < len; ++i) {
        float4 acc, xn = xcur;
        if (fused) {
            acc = xcur;
            if (i + 1 < len) xn = Xp4[((size_t)b * Iq + i + 1) * 256 + tid];
        } else {
            xs[tid] = instr_repr[((size_t)b * Iq + i) * Hq + tid];
            acc = bb;
            __syncthreads();  // xs ready
            const float4* Wp = Wih4i + tid;
            #pragma unroll 4
            for (int k = 0; k < Hq; ++k) {
                float4 wv = Wp[k * 256];
                float xv = xs[k];
                acc.x += wv.x * xv; acc.y += wv.y * xv;
                acc.z += wv.z * xv; acc.w += wv.w * xv;
            }
        }
        const float4* Wh = Whh4i + tid;
        #pragma unroll 4
        for (int k = 0; k < Hq; ++k) {
            float4 wv = Wh[k * 256];
            float hv = hs[k];
            acc.x += wv.x * hv; acc.y += wv.y * hv;
            acc.z += wv.z * hv; acc.w += wv.w * hv;
        }
        __syncthreads();  // done reading hs (and xs)
        float cn = sigf(acc.y) * cc + sigf(acc.x) * tanh_fast(acc.z);
        cc = cn;
        hs[tid] = sigf(acc.w) * tanh_fast(cn);
        xcur = xn;
        __syncthreads();  // hs visible
    }

    float p = linW[tid] * hs[tid];
    #pragma unroll
    for (int off = 32; off > 0; off >>= 1) p += __shfl_down(p, off);
    if ((tid & 63) == 0) red[tid >> 6] = p;
    __syncthreads();
    if (tid == 0) out[b] = red[0] + red[1] + red[2] + red[3] + linb[0];
}

// ---------------------------------------------------------------------------
extern "C" void kernel_launch(void* const* d_in, const int* in_sizes, int n_in,
                              void* d_out, int out_size, void* d_ws, size_t ws_size,
                              hipStream_t stream) {
    const int*   tokens  = (const int*)d_in[0];
    const int*   icnt    = (const int*)d_in[1];
    const int*   tcnt    = (const int*)d_in[2];
    const float* emb     = (const float*)d_in[3];
    const float* Wih_tok = (const float*)d_in[4];
    const float* Whh_tok = (const float*)d_in[5];
    const float* b_tok   = (const float*)d_in[6];
    const float* Wih_ins = (const float*)d_in[7];
    const float* Whh_ins = (const float*)d_in[8];
    const float* b_ins   = (const float*)d_in[9];
    const float* linW    = (const float*)d_in[10];
    const float* linb    = (const float*)d_in[11];
    float* out = (float*)d_out;

    float* ws = (float*)d_ws;
    // layout (floats)
    float* Wih4t = ws;                    // 262144
    float* Whh4t = Wih4t + 262144;        // 262144
    float* Wih4i = Whh4t + 262144;        // 262144
    float* Whh4i = Wih4i + 262144;        // 262144
    float* b4t   = Whh4i + 262144;        // 1024
    float* b4i   = b4t + 1024;            // 1024
    float* Ep4   = b4i + 1024;            // 4194304
    float* irepr = Ep4 + 4194304;         // 4194304
    float* Xp4   = irepr + 4194304;       // 16777216 (fast path only)

    size_t need_fb   = (size_t)(262144 * 4 + 2048 + 4194304 * 2) * 4;
    size_t need_fast = need_fb + (size_t)16777216 * 4;
    if (ws_size < need_fb) return;  // fail loudly
    int fast = (ws_size >= need_fast) ? 1 : 0;

    hipLaunchKernelGGL(k_pack, dim3(1024), dim3(256), 0, stream,
                       Wih_tok, Whh_tok, Wih_ins, Whh_ins, b_tok, b_ins,
                       Wih4t, Whh4t, Wih4i, Whh4i, b4t, b4i);
    hipLaunchKernelGGL(k_epre, dim3(512), dim3(256), 0, stream,
                       emb, (const float4*)Wih4t, (const float4*)b4t, (float4*)Ep4);
    hipLaunchKernelGGL(k_token_lstm, dim3(1024), dim3(256), 0, stream,
                       tokens, tcnt, (const float4*)Ep4, (const float4*)Whh4t,
                       (const float4*)Wih4i, (const float4*)b4i,
                       irepr, (float4*)Xp4, fast);
    hipLaunchKernelGGL(k_instr_lstm, dim3(256), dim3(256), 0, stream,
                       (const float4*)Xp4, irepr, icnt,
                       (const float4*)Wih4i, (const float4*)Whh4i,
                       (const float4*)b4i, linW, linb, out, fast);
}